// Round 1
// baseline (6000.069 us; speedup 1.0000x reference)
//
#include <hip/hip_runtime.h>
#include <math.h>

#define S_ 2048
#define E_ 512
#define H_ 8
#define L_ 4
#define F_ 2048
#define V_ 32000
#define B_ 2
#define M_ (B_*S_)   // 4096 token rows

// ---------------------------------------------------------------------------
// Embedding: h[b,s,:] = tok_emb[x[b,s],:] + pos_emb[0,s,:]
// grid = M_ blocks, 128 threads (512 floats = 1 float4/thread)
// ---------------------------------------------------------------------------
__global__ __launch_bounds__(128) void embed_k(const int* __restrict__ x,
                                               const float* __restrict__ tok,
                                               const float* __restrict__ pos,
                                               float* __restrict__ h)
{
    const int t = blockIdx.x;          // token row 0..4095
    const int sidx = t & (S_ - 1);     // position within sequence
    const int tid = threadIdx.x;
    const int id = x[t];
    float4 a = *(const float4*)&tok[(size_t)id * E_ + tid * 4];
    float4 p = *(const float4*)&pos[(size_t)sidx * E_ + tid * 4];
    float4 r = {a.x + p.x, a.y + p.y, a.z + p.z, a.w + p.w};
    *(float4*)&h[(size_t)t * E_ + tid * 4] = r;
}

// ---------------------------------------------------------------------------
// LayerNorm (two-pass, matches reference mean/var semantics exactly)
// one block (128 threads) per row of 512
// ---------------------------------------------------------------------------
__global__ __launch_bounds__(128) void ln_k(const float* __restrict__ in,
                                            const float* __restrict__ w,
                                            const float* __restrict__ bta,
                                            float* __restrict__ out)
{
    const int row = blockIdx.x;
    const int tid = threadIdx.x;
    const float4 v = *(const float4*)&in[(size_t)row * E_ + tid * 4];

    float s = v.x + v.y + v.z + v.w;
#pragma unroll
    for (int off = 1; off < 64; off <<= 1) s += __shfl_xor(s, off, 64);
    __shared__ float red[2];
    if ((tid & 63) == 0) red[tid >> 6] = s;
    __syncthreads();
    const float mean = (red[0] + red[1]) * (1.0f / E_);

    const float dx = v.x - mean, dy = v.y - mean, dz = v.z - mean, dw = v.w - mean;
    float ss = dx * dx + dy * dy + dz * dz + dw * dw;
#pragma unroll
    for (int off = 1; off < 64; off <<= 1) ss += __shfl_xor(ss, off, 64);
    __shared__ float red2[2];
    if ((tid & 63) == 0) red2[tid >> 6] = ss;
    __syncthreads();
    const float rstd = rsqrtf((red2[0] + red2[1]) * (1.0f / E_) + 1e-5f);

    const float4 wv = *(const float4*)&w[tid * 4];
    const float4 bv = *(const float4*)&bta[tid * 4];
    float4 ov;
    ov.x = dx * rstd * wv.x + bv.x;
    ov.y = dy * rstd * wv.y + bv.y;
    ov.z = dz * rstd * wv.z + bv.z;
    ov.w = dw * rstd * wv.w + bv.w;
    *(float4*)&out[(size_t)row * E_ + tid * 4] = ov;
}

// ---------------------------------------------------------------------------
// Tiled fp32 GEMM: C[M,N] = A[M,K] @ B[K,N] + bias  (+ GELU or + residual)
// 256 threads, tx=tid%16 (N dir), ty=tid/16 (M dir)
// thread computes RT x CT sub-blocks of 4x4, sub-block stride BM/RT, BN/CT
// EPI: 0 = bias only, 1 = bias + exact GELU, 2 = bias + residual add
// All problem dims divide the tiles exactly -> no bounds checks.
// ---------------------------------------------------------------------------
template<int BM, int BN, int BK, int RT, int CT, int EPI>
__global__ __launch_bounds__(256) void gemm_k(const float* __restrict__ A,
                                              const float* __restrict__ Bm,
                                              const float* __restrict__ bias,
                                              const float* __restrict__ res,
                                              float* __restrict__ C,
                                              int M, int N, int K)
{
    __shared__ float As[BK][BM];   // A stored transposed: As[k][m]
    __shared__ float Bs[BK][BN];

    const int tid = threadIdx.x;
    const int tx = tid & 15;
    const int ty = tid >> 4;
    const int brow = blockIdx.y * BM;
    const int bcol = blockIdx.x * BN;

    float acc[RT * 4][CT * 4] = {};

    constexpr int APT = BM * BK / 1024;   // float4 loads per thread (A tile)
    constexpr int BPT = BK * BN / 1024;

    for (int k0 = 0; k0 < K; k0 += BK) {
#pragma unroll
        for (int i = 0; i < APT; i++) {
            int v = tid + i * 256;
            int r  = v / (BK / 4);
            int c4 = (v % (BK / 4)) * 4;
            float4 t = *(const float4*)&A[(size_t)(brow + r) * K + k0 + c4];
            As[c4 + 0][r] = t.x;
            As[c4 + 1][r] = t.y;
            As[c4 + 2][r] = t.z;
            As[c4 + 3][r] = t.w;
        }
#pragma unroll
        for (int i = 0; i < BPT; i++) {
            int v = tid + i * 256;
            int r  = v / (BN / 4);
            int c4 = (v % (BN / 4)) * 4;
            *(float4*)&Bs[r][c4] =
                *(const float4*)&Bm[(size_t)(k0 + r) * N + bcol + c4];
        }
        __syncthreads();

#pragma unroll
        for (int kk = 0; kk < BK; kk++) {
            float ar[RT * 4], br[CT * 4];
#pragma unroll
            for (int s = 0; s < RT; s++)
                *(float4*)&ar[s * 4] = *(const float4*)&As[kk][s * (BM / RT) + ty * 4];
#pragma unroll
            for (int t = 0; t < CT; t++)
                *(float4*)&br[t * 4] = *(const float4*)&Bs[kk][t * (BN / CT) + tx * 4];
#pragma unroll
            for (int i = 0; i < RT * 4; i++)
#pragma unroll
                for (int j = 0; j < CT * 4; j++)
                    acc[i][j] = fmaf(ar[i], br[j], acc[i][j]);
        }
        __syncthreads();
    }

    // epilogue
#pragma unroll
    for (int i = 0; i < RT * 4; i++) {
        const int row = brow + (i >> 2) * (BM / RT) + ty * 4 + (i & 3);
#pragma unroll
        for (int t = 0; t < CT; t++) {
            const int col = bcol + t * (BN / CT) + tx * 4;
            const float4 b4 = *(const float4*)&bias[col];
            float o0 = acc[i][t * 4 + 0] + b4.x;
            float o1 = acc[i][t * 4 + 1] + b4.y;
            float o2 = acc[i][t * 4 + 2] + b4.z;
            float o3 = acc[i][t * 4 + 3] + b4.w;
            if constexpr (EPI == 1) {   // exact GELU: x*0.5*(1+erf(x/sqrt(2)))
                o0 = o0 * 0.5f * (1.0f + erff(o0 * 0.70710678118654752f));
                o1 = o1 * 0.5f * (1.0f + erff(o1 * 0.70710678118654752f));
                o2 = o2 * 0.5f * (1.0f + erff(o2 * 0.70710678118654752f));
                o3 = o3 * 0.5f * (1.0f + erff(o3 * 0.70710678118654752f));
            }
            if constexpr (EPI == 2) {
                const float4 r4 = *(const float4*)&res[(size_t)row * N + col];
                o0 += r4.x; o1 += r4.y; o2 += r4.z; o3 += r4.w;
            }
            float4 ov = {o0, o1, o2, o3};
            *(float4*)&C[(size_t)row * N + col] = ov;
        }
    }
}

// ---------------------------------------------------------------------------
// Causal flash attention, fp32.
// qkv layout per token row (1536 floats): [3][H][D] -> q at h*64, k at 512+h*64,
// v at 1024+h*64.  grid = (S/64, B*H), 256 threads.
// Thread (r = tid/4, c = tid%4): query row q0+r, dim chunk c*16..c*16+15.
// K/V tiles of 64 rows staged in LDS; online softmax per row (4-lane redundant).
// ---------------------------------------------------------------------------
__global__ __launch_bounds__(256) void attn_k(const float* __restrict__ qkv,
                                              float* __restrict__ o)
{
    __shared__ float Ks[64][64];
    __shared__ float Vs[64][64];

    const int tid = threadIdx.x;
    const int r = tid >> 2;            // local query row 0..63
    const int c = tid & 3;             // dim chunk 0..3
    const int q0 = blockIdx.x * 64;
    const int bh = blockIdx.y;
    const int b  = bh / H_;
    const int hh = bh % H_;
    const int qrow = q0 + r;
    const size_t base = (size_t)b * S_ * 1536;

    float q[16];
    {
        const float* qptr = &qkv[base + (size_t)qrow * 1536 + hh * 64 + c * 16];
#pragma unroll
        for (int i = 0; i < 16; i += 4) *(float4*)&q[i] = *(const float4*)&qptr[i];
    }

    float oa[16] = {};
    float m = -INFINITY, l = 0.0f;
    const float scale = 0.125f;        // 1/sqrt(64)

    for (int k0 = 0; k0 <= q0; k0 += 64) {
        // stage K and V tiles (64x64 each)
#pragma unroll
        for (int i = 0; i < 4; i++) {
            int v  = i * 256 + tid;     // float4 index in 64*64/4
            int kr = v >> 4;
            int kc = (v & 15) * 4;
            const size_t rowb = base + (size_t)(k0 + kr) * 1536 + hh * 64 + kc;
            *(float4*)&Ks[kr][kc] = *(const float4*)&qkv[rowb + 512];
            *(float4*)&Vs[kr][kc] = *(const float4*)&qkv[rowb + 1024];
        }
        __syncthreads();

        const int jmax = min(64, qrow - k0 + 1);   // causal limit within tile
        for (int j = 0; j < jmax; j++) {
            float s = 0.0f;
#pragma unroll
            for (int d = 0; d < 16; d++) s = fmaf(q[d], Ks[j][c * 16 + d], s);
            s += __shfl_xor(s, 1, 64);
            s += __shfl_xor(s, 2, 64);
            s *= scale;
            if (s > m) {
                const float sc = __expf(m - s);     // 0 on first iter (m=-inf)
                l = l * sc + 1.0f;
#pragma unroll
                for (int d = 0; d < 16; d++)
                    oa[d] = fmaf(oa[d], sc, Vs[j][c * 16 + d]);
                m = s;
            } else {
                const float p = __expf(s - m);
                l += p;
#pragma unroll
                for (int d = 0; d < 16; d++)
                    oa[d] = fmaf(p, Vs[j][c * 16 + d], oa[d]);
            }
        }
        __syncthreads();
    }

    const float inv = 1.0f / l;
    float* optr = &o[((size_t)b * S_ + qrow) * E_ + hh * 64 + c * 16];
#pragma unroll
    for (int d = 0; d < 16; d += 4) {
        float4 ov = {oa[d] * inv, oa[d + 1] * inv, oa[d + 2] * inv, oa[d + 3] * inv};
        *(float4*)&optr[d] = ov;
    }
}

// ---------------------------------------------------------------------------
// Host-side launch
// ---------------------------------------------------------------------------
extern "C" void kernel_launch(void* const* d_in, const int* in_sizes, int n_in,
                              void* d_out, int out_size, void* d_ws, size_t ws_size,
                              hipStream_t stream)
{
    (void)in_sizes; (void)n_in; (void)out_size; (void)ws_size;

    const int*   x     = (const int*)d_in[0];
    const float* tok   = (const float*)d_in[1];
    const float* pos   = (const float*)d_in[2];
    const float* ln1w  = (const float*)d_in[3];
    const float* ln1b  = (const float*)d_in[4];
    const float* qkvw  = (const float*)d_in[5];
    const float* qkvb  = (const float*)d_in[6];
    const float* projw = (const float*)d_in[7];
    const float* projb = (const float*)d_in[8];
    const float* ln2w  = (const float*)d_in[9];
    const float* ln2b  = (const float*)d_in[10];
    const float* ff1w  = (const float*)d_in[11];
    const float* ff1b  = (const float*)d_in[12];
    const float* ff2w  = (const float*)d_in[13];
    const float* ff2b  = (const float*)d_in[14];
    const float* lnfw  = (const float*)d_in[15];
    const float* lnfb  = (const float*)d_in[16];
    const float* outw  = (const float*)d_in[17];
    const float* outb  = (const float*)d_in[18];

    float* out = (float*)d_out;
    float* ws  = (float*)d_ws;

    float* h   = ws;                       // [4096, 512]
    float* y   = h   + (size_t)M_ * E_;    // [4096, 512]
    float* qkv = y   + (size_t)M_ * E_;    // [4096, 1536]
    float* o   = qkv + (size_t)M_ * 3 * E_;// [4096, 512]
    float* ff  = o   + (size_t)M_ * E_;    // [4096, 2048]

    embed_k<<<M_, 128, 0, stream>>>(x, tok, pos, h);

    for (int l = 0; l < L_; l++) {
        ln_k<<<M_, 128, 0, stream>>>(h, ln1w + (size_t)l * E_, ln1b + (size_t)l * E_, y);

        gemm_k<128, 128, 8, 2, 2, 0><<<dim3(3 * E_ / 128, M_ / 128), 256, 0, stream>>>(
            y, qkvw + (size_t)l * E_ * 3 * E_, qkvb + (size_t)l * 3 * E_,
            nullptr, qkv, M_, 3 * E_, E_);

        attn_k<<<dim3(S_ / 64, B_ * H_), 256, 0, stream>>>(qkv, o);

        gemm_k<64, 64, 16, 1, 1, 2><<<dim3(E_ / 64, M_ / 64), 256, 0, stream>>>(
            o, projw + (size_t)l * E_ * E_, projb + (size_t)l * E_,
            h, h, M_, E_, E_);

        ln_k<<<M_, 128, 0, stream>>>(h, ln2w + (size_t)l * E_, ln2b + (size_t)l * E_, y);

        gemm_k<128, 128, 8, 2, 2, 1><<<dim3(F_ / 128, M_ / 128), 256, 0, stream>>>(
            y, ff1w + (size_t)l * E_ * F_, ff1b + (size_t)l * F_,
            nullptr, ff, M_, F_, E_);

        gemm_k<64, 64, 16, 1, 1, 2><<<dim3(E_ / 64, M_ / 64), 256, 0, stream>>>(
            ff, ff2w + (size_t)l * F_ * E_, ff2b + (size_t)l * E_,
            h, h, M_, E_, F_);
    }

    ln_k<<<M_, 128, 0, stream>>>(h, lnfw, lnfb, y);

    gemm_k<128, 128, 8, 2, 2, 0><<<dim3(V_ / 128, M_ / 128), 256, 0, stream>>>(
        y, outw, outb, nullptr, out, M_, V_, E_);
}

// Round 4
// 3935.151 us; speedup vs baseline: 1.5247x; 1.5247x over previous
//
#include <hip/hip_runtime.h>
#include <math.h>

#define S_ 2048
#define E_ 512
#define H_ 8
#define L_ 4
#define F_ 2048
#define V_ 32000
#define B_ 2
#define M_ (B_*S_)   // 4096 token rows

typedef short s16x8 __attribute__((ext_vector_type(8)));
typedef float f32x4 __attribute__((ext_vector_type(4)));
typedef unsigned short u16x8 __attribute__((ext_vector_type(8)));
typedef unsigned short u16x4 __attribute__((ext_vector_type(4)));

// fp32 -> bf16 (RNE) and back
__device__ __forceinline__ unsigned short f2bf(float f) {
    union { float f; unsigned u; } v; v.f = f;
    unsigned r = v.u + 0x7fffu + ((v.u >> 16) & 1u);
    return (unsigned short)(r >> 16);
}
__device__ __forceinline__ float bf2f(unsigned short b) {
    union { unsigned u; float f; } v; v.u = ((unsigned)b) << 16;
    return v.f;
}

__device__ __forceinline__ void gload_lds16(const void* g, void* l) {
    typedef const __attribute__((address_space(1))) unsigned int* gp_t;
    typedef __attribute__((address_space(3))) unsigned int* lp_t;
    __builtin_amdgcn_global_load_lds((gp_t)g, (lp_t)l, 16, 0, 0);
}

// ---------------------------------------------------------------------------
// Embedding: h[b,s,:] = tok_emb[x[b,s],:] + pos_emb[0,s,:]  (fp32)
// ---------------------------------------------------------------------------
__global__ __launch_bounds__(128) void embed_k(const int* __restrict__ x,
                                               const float* __restrict__ tok,
                                               const float* __restrict__ pos,
                                               float* __restrict__ h)
{
    const int t = blockIdx.x;
    const int sidx = t & (S_ - 1);
    const int tid = threadIdx.x;
    const int id = x[t];
    float4 a = *(const float4*)&tok[(size_t)id * E_ + tid * 4];
    float4 p = *(const float4*)&pos[(size_t)sidx * E_ + tid * 4];
    float4 r = {a.x + p.x, a.y + p.y, a.z + p.z, a.w + p.w};
    *(float4*)&h[(size_t)t * E_ + tid * 4] = r;
}

// ---------------------------------------------------------------------------
// LayerNorm fp32 in -> bf16 out. One 128-thread block per row of 512.
// ---------------------------------------------------------------------------
__global__ __launch_bounds__(128) void ln_k(const float* __restrict__ in,
                                            const float* __restrict__ w,
                                            const float* __restrict__ bta,
                                            unsigned short* __restrict__ out)
{
    const int row = blockIdx.x;
    const int tid = threadIdx.x;
    const float4 v = *(const float4*)&in[(size_t)row * E_ + tid * 4];

    float s = v.x + v.y + v.z + v.w;
#pragma unroll
    for (int off = 1; off < 64; off <<= 1) s += __shfl_xor(s, off, 64);
    __shared__ float red[2];
    if ((tid & 63) == 0) red[tid >> 6] = s;
    __syncthreads();
    const float mean = (red[0] + red[1]) * (1.0f / E_);

    const float dx = v.x - mean, dy = v.y - mean, dz = v.z - mean, dw = v.w - mean;
    float ss = dx * dx + dy * dy + dz * dz + dw * dw;
#pragma unroll
    for (int off = 1; off < 64; off <<= 1) ss += __shfl_xor(ss, off, 64);
    __shared__ float red2[2];
    if ((tid & 63) == 0) red2[tid >> 6] = ss;
    __syncthreads();
    const float rstd = rsqrtf((red2[0] + red2[1]) * (1.0f / E_) + 1e-5f);

    const float4 wv = *(const float4*)&w[tid * 4];
    const float4 bv = *(const float4*)&bta[tid * 4];
    u16x4 ov;
    ov[0] = f2bf(dx * rstd * wv.x + bv.x);
    ov[1] = f2bf(dy * rstd * wv.y + bv.y);
    ov[2] = f2bf(dz * rstd * wv.z + bv.z);
    ov[3] = f2bf(dw * rstd * wv.w + bv.w);
    *(u16x4*)&out[(size_t)row * E_ + tid * 4] = ov;
}

// ---------------------------------------------------------------------------
// Weight transpose + convert: W[K][N] fp32 -> WT[N][K] bf16. 32x32 LDS tiles.
// ---------------------------------------------------------------------------
__global__ __launch_bounds__(256) void wt_k(const float* __restrict__ W,
                                            unsigned short* __restrict__ WT,
                                            int K, int N)
{
    __shared__ float t[32][33];
    const int n0 = blockIdx.x * 32, k0 = blockIdx.y * 32;
    const int c = threadIdx.x & 31, r8 = threadIdx.x >> 5;
#pragma unroll
    for (int i = 0; i < 4; i++) {
        int k = r8 + i * 8;
        t[k][c] = W[(size_t)(k0 + k) * N + n0 + c];
    }
    __syncthreads();
#pragma unroll
    for (int i = 0; i < 4; i++) {
        int n = r8 + i * 8;
        WT[(size_t)(n0 + n) * K + k0 + c] = f2bf(t[c][n]);
    }
}

// ---------------------------------------------------------------------------
// bf16 MFMA GEMM: C[M,N] = A[M,K] @ BT[N,K]^T  (A,BT bf16 row-major)
// Tile BM x BN (BM=WM*64, BN=WN*64), BK=32, waves arranged WM x WN,
// each wave computes 64x64 = 4x4 frags of 16x16 via mfma_f32_16x16x32_bf16.
// global_load_lds width-16 staging, single-buffered (m97 structure).
// EPI: 0 = bias -> fp32 out; 1 = bias+GELU -> bf16 out;
//      2 = bias + residual, in-place fp32 resC; 3 = bias -> bf16 out
// ---------------------------------------------------------------------------
template<int WM, int WN, int EPI>
__global__ __launch_bounds__(WM*WN*64) void bgemm_k(
    const unsigned short* __restrict__ A,
    const unsigned short* __restrict__ BT,
    const float* __restrict__ bias,
    float* __restrict__ resC,
    unsigned short* __restrict__ outB,
    int M, int N, int K)
{
    constexpr int BM = WM * 64, BN = WN * 64, NW = WM * WN;
    constexpr int AISS = BM / 16, NISS = (BM + BN) / 16, IPW = NISS / NW;
    __shared__ unsigned short As[BM][32];
    __shared__ unsigned short Bs[BN][32];

    const int tid = threadIdx.x;
    const int lane = tid & 63;
    const int w = tid >> 6;
    const int wr = w / WN, wc = w % WN;
    const int brow = blockIdx.y * BM, bcol = blockIdx.x * BN;

    const int lrow = lane >> 2;          // staging: row within 16-row group
    const int lcol = (lane & 3) * 8;     // staging: bf16 col offset (16B chunks)
    const int fr = lane & 15;            // fragment row/col within 16
    const int fk = (lane >> 4) * 8;      // fragment k offset

    f32x4 acc[4][4] = {};

    for (int k0 = 0; k0 < K; k0 += 32) {
#pragma unroll
        for (int ii = 0; ii < IPW; ii++) {
            const int i = w + ii * NW;
            if (i < AISS) {
                const unsigned short* g = &A[(size_t)(brow + i * 16 + lrow) * K + k0 + lcol];
                gload_lds16(g, &As[i * 16][0]);
            } else {
                const int r = i - AISS;
                const unsigned short* g = &BT[(size_t)(bcol + r * 16 + lrow) * K + k0 + lcol];
                gload_lds16(g, &Bs[r * 16][0]);
            }
        }
        __syncthreads();

        s16x8 af[4], bfr[4];
#pragma unroll
        for (int m = 0; m < 4; m++)
            af[m] = *(const s16x8*)&As[wr * 64 + m * 16 + fr][fk];
#pragma unroll
        for (int n = 0; n < 4; n++)
            bfr[n] = *(const s16x8*)&Bs[wc * 64 + n * 16 + fr][fk];
#pragma unroll
        for (int m = 0; m < 4; m++)
#pragma unroll
            for (int n = 0; n < 4; n++)
                acc[m][n] = __builtin_amdgcn_mfma_f32_16x16x32_bf16(af[m], bfr[n], acc[m][n], 0, 0, 0);
        __syncthreads();
    }

    // epilogue: row = brow + wr*64 + m*16 + (lane>>4)*4 + j ; col = bcol + wc*64 + n*16 + (lane&15)
    const int rbase = brow + wr * 64 + (lane >> 4) * 4;
    const int cbase = bcol + wc * 64 + (lane & 15);
#pragma unroll
    for (int n = 0; n < 4; n++) {
        const int col = cbase + n * 16;
        const float bz = bias[col];
#pragma unroll
        for (int m = 0; m < 4; m++) {
#pragma unroll
            for (int j = 0; j < 4; j++) {
                const int row = rbase + m * 16 + j;
                float v = acc[m][n][j] + bz;
                if constexpr (EPI == 0) {
                    resC[(size_t)row * N + col] = v;
                } else if constexpr (EPI == 1) {
                    v = v * 0.5f * (1.0f + erff(v * 0.70710678118654752f));
                    outB[(size_t)row * N + col] = f2bf(v);
                } else if constexpr (EPI == 2) {
                    float* p = &resC[(size_t)row * N + col];
                    *p = *p + v;
                } else {
                    outB[(size_t)row * N + col] = f2bf(v);
                }
            }
        }
    }
}

// ---------------------------------------------------------------------------
// Causal flash attention; bf16 qkv in, bf16 o out, fp32 math.
// qkv row layout (1536 bf16): q at h*64, k at 512+h*64, v at 1024+h*64.
// grid = (S/32, B*H), 256 threads. Thread (r=tid>>3, c=tid&7): query row
// q0+r, dims c*8..c*8+7. K/V tiles of 64 keys staged in LDS (bf16).
// ---------------------------------------------------------------------------
__global__ __launch_bounds__(256) void attn_k(const unsigned short* __restrict__ qkv,
                                              unsigned short* __restrict__ o)
{
    __shared__ unsigned short Ks[64][64];
    __shared__ unsigned short Vs[64][64];

    const int tid = threadIdx.x;
    const int r = tid >> 3;            // local query row 0..31
    const int c = tid & 7;             // dim chunk 0..7
    const int q0 = blockIdx.x * 32;
    const int bh = blockIdx.y;
    const int b  = bh / H_;
    const int hh = bh % H_;
    const int qrow = q0 + r;
    const size_t base = (size_t)b * S_ * 1536;

    float q[8];
    {
        u16x8 qb = *(const u16x8*)&qkv[base + (size_t)qrow * 1536 + hh * 64 + c * 8];
#pragma unroll
        for (int d = 0; d < 8; d++) q[d] = bf2f(qb[d]);
    }

    float oa[8] = {};
    float m = -INFINITY, l = 0.0f;
    const float scale = 0.125f;        // 1/sqrt(64)

    for (int k0 = 0; k0 <= q0; k0 += 64) {
#pragma unroll
        for (int i = 0; i < 2; i++) {
            int v  = i * 256 + tid;     // 16B chunk id, 0..511
            int kr = v >> 3;
            int kc = (v & 7) * 8;
            const size_t rowb = base + (size_t)(k0 + kr) * 1536 + hh * 64 + kc;
            *(uint4*)&Ks[kr][kc] = *(const uint4*)&qkv[rowb + 512];
            *(uint4*)&Vs[kr][kc] = *(const uint4*)&qkv[rowb + 1024];
        }
        __syncthreads();

        const int jmax = min(64, qrow - k0 + 1);
        for (int j = 0; j < jmax; j++) {
            u16x8 kb = *(const u16x8*)&Ks[j][c * 8];
            float s = 0.0f;
#pragma unroll
            for (int d = 0; d < 8; d++) s = fmaf(q[d], bf2f(kb[d]), s);
            s += __shfl_xor(s, 1, 8);
            s += __shfl_xor(s, 2, 8);
            s += __shfl_xor(s, 4, 8);
            s *= scale;
            u16x8 vb = *(const u16x8*)&Vs[j][c * 8];
            if (s > m) {
                const float sc = __expf(m - s);
                l = l * sc + 1.0f;
#pragma unroll
                for (int d = 0; d < 8; d++)
                    oa[d] = fmaf(oa[d], sc, bf2f(vb[d]));
                m = s;
            } else {
                const float p = __expf(s - m);
                l += p;
#pragma unroll
                for (int d = 0; d < 8; d++)
                    oa[d] = fmaf(p, bf2f(vb[d]), oa[d]);
            }
        }
        __syncthreads();
    }

    const float inv = 1.0f / l;
    u16x8 ob8;
#pragma unroll
    for (int d = 0; d < 8; d++) ob8[d] = f2bf(oa[d] * inv);
    *(u16x8*)&o[((size_t)b * S_ + qrow) * E_ + hh * 64 + c * 8] = ob8;
}

// ---------------------------------------------------------------------------
// Host-side launch
// ---------------------------------------------------------------------------
extern "C" void kernel_launch(void* const* d_in, const int* in_sizes, int n_in,
                              void* d_out, int out_size, void* d_ws, size_t ws_size,
                              hipStream_t stream)
{
    (void)in_sizes; (void)n_in; (void)out_size; (void)ws_size;

    const int*   x     = (const int*)d_in[0];
    const float* tok   = (const float*)d_in[1];
    const float* pos   = (const float*)d_in[2];
    const float* ln1w  = (const float*)d_in[3];
    const float* ln1b  = (const float*)d_in[4];
    const float* qkvw  = (const float*)d_in[5];
    const float* qkvb  = (const float*)d_in[6];
    const float* projw = (const float*)d_in[7];
    const float* projb = (const float*)d_in[8];
    const float* ln2w  = (const float*)d_in[9];
    const float* ln2b  = (const float*)d_in[10];
    const float* ff1w  = (const float*)d_in[11];
    const float* ff1b  = (const float*)d_in[12];
    const float* ff2w  = (const float*)d_in[13];
    const float* ff2b  = (const float*)d_in[14];
    const float* lnfw  = (const float*)d_in[15];
    const float* lnfb  = (const float*)d_in[16];
    const float* outw  = (const float*)d_in[17];
    const float* outb  = (const float*)d_in[18];

    float* out = (float*)d_out;
    char*  w8  = (char*)d_ws;

    // workspace layout (78.9 MB total; round-1 proved >= 83.9 MB available)
    float*          h    = (float*)w8;                                   //  8,388,608 B
    unsigned short* qkvB = (unsigned short*)(w8 + 8388608);              // 12,582,912 B
    unsigned short* yb   = (unsigned short*)(w8 + 8388608 + 12582912);   //  4,194,304 B
    unsigned short* ffb  = (unsigned short*)(w8 + 25165824);             // 16,777,216 B
    unsigned short* ob   = (unsigned short*)(w8 + 41943040);             //  4,194,304 B
    unsigned short* wt   = (unsigned short*)(w8 + 46137344);             // 32,768,000 B

    embed_k<<<M_, 128, 0, stream>>>(x, tok, pos, h);

    for (int l = 0; l < L_; l++) {
        ln_k<<<M_, 128, 0, stream>>>(h, ln1w + (size_t)l * E_, ln1b + (size_t)l * E_, yb);

        wt_k<<<dim3(3 * E_ / 32, E_ / 32), 256, 0, stream>>>(
            qkvw + (size_t)l * E_ * 3 * E_, wt, E_, 3 * E_);
        bgemm_k<2, 2, 3><<<dim3(3 * E_ / 128, M_ / 128), 256, 0, stream>>>(
            yb, wt, qkvb + (size_t)l * 3 * E_, nullptr, qkvB, M_, 3 * E_, E_);

        attn_k<<<dim3(S_ / 32, B_ * H_), 256, 0, stream>>>(qkvB, ob);

        wt_k<<<dim3(E_ / 32, E_ / 32), 256, 0, stream>>>(
            projw + (size_t)l * E_ * E_, wt, E_, E_);
        bgemm_k<2, 1, 2><<<dim3(E_ / 64, M_ / 128), 128, 0, stream>>>(
            ob, wt, projb + (size_t)l * E_, h, nullptr, M_, E_, E_);

        ln_k<<<M_, 128, 0, stream>>>(h, ln2w + (size_t)l * E_, ln2b + (size_t)l * E_, yb);

        wt_k<<<dim3(F_ / 32, E_ / 32), 256, 0, stream>>>(
            ff1w + (size_t)l * E_ * F_, wt, E_, F_);
        bgemm_k<2, 2, 1><<<dim3(F_ / 128, M_ / 128), 256, 0, stream>>>(
            yb, wt, ff1b + (size_t)l * F_, nullptr, ffb, M_, F_, E_);

        wt_k<<<dim3(E_ / 32, F_ / 32), 256, 0, stream>>>(
            ff2w + (size_t)l * F_ * E_, wt, F_, E_);
        bgemm_k<2, 1, 2><<<dim3(E_ / 64, M_ / 128), 128, 0, stream>>>(
            ffb, wt, ff2b + (size_t)l * E_, h, nullptr, M_, E_, F_);
    }

    ln_k<<<M_, 128, 0, stream>>>(h, lnfw, lnfb, yb);

    wt_k<<<dim3(V_ / 32, E_ / 32), 256, 0, stream>>>(outw, wt, E_, V_);
    bgemm_k<2, 2, 0><<<dim3(V_ / 128, M_ / 128), 256, 0, stream>>>(
        yb, wt, outb, out, nullptr, M_, V_, E_);
}

// Round 7
// 1792.037 us; speedup vs baseline: 3.3482x; 2.1959x over previous
//
#include <hip/hip_runtime.h>
#include <math.h>

#define S_ 2048
#define E_ 512
#define H_ 8
#define L_ 4
#define F_ 2048
#define V_ 32000
#define B_ 2
#define M_ (B_*S_)   // 4096 token rows

typedef short s16x8 __attribute__((ext_vector_type(8)));
typedef float f32x4 __attribute__((ext_vector_type(4)));
typedef unsigned short u16x8 __attribute__((ext_vector_type(8)));
typedef unsigned short u16x4 __attribute__((ext_vector_type(4)));

// fp32 -> bf16 (RNE) and back
__device__ __forceinline__ unsigned short f2bf(float f) {
    union { float f; unsigned u; } v; v.f = f;
    unsigned r = v.u + 0x7fffu + ((v.u >> 16) & 1u);
    return (unsigned short)(r >> 16);
}
__device__ __forceinline__ float bf2f(unsigned short b) {
    union { unsigned u; float f; } v; v.u = ((unsigned)b) << 16;
    return v.f;
}

__device__ __forceinline__ void gload_lds16(const void* g, void* l) {
    typedef const __attribute__((address_space(1))) unsigned int* gp_t;
    typedef __attribute__((address_space(3))) unsigned int* lp_t;
    __builtin_amdgcn_global_load_lds((gp_t)g, (lp_t)l, 16, 0, 0);
}

// ---------------------------------------------------------------------------
// Embedding: h[b,s,:] = tok_emb[x[b,s],:] + pos_emb[0,s,:]  (fp32)
// ---------------------------------------------------------------------------
__global__ __launch_bounds__(128) void embed_k(const int* __restrict__ x,
                                               const float* __restrict__ tok,
                                               const float* __restrict__ pos,
                                               float* __restrict__ h)
{
    const int t = blockIdx.x;
    const int sidx = t & (S_ - 1);
    const int tid = threadIdx.x;
    const int id = x[t];
    float4 a = *(const float4*)&tok[(size_t)id * E_ + tid * 4];
    float4 p = *(const float4*)&pos[(size_t)sidx * E_ + tid * 4];
    float4 r = {a.x + p.x, a.y + p.y, a.z + p.z, a.w + p.w};
    *(float4*)&h[(size_t)t * E_ + tid * 4] = r;
}

// ---------------------------------------------------------------------------
// LayerNorm fp32 in -> bf16 out. One 128-thread block per row of 512.
// ---------------------------------------------------------------------------
__global__ __launch_bounds__(128) void ln_k(const float* __restrict__ in,
                                            const float* __restrict__ w,
                                            const float* __restrict__ bta,
                                            unsigned short* __restrict__ out)
{
    const int row = blockIdx.x;
    const int tid = threadIdx.x;
    const float4 v = *(const float4*)&in[(size_t)row * E_ + tid * 4];

    float s = v.x + v.y + v.z + v.w;
#pragma unroll
    for (int off = 1; off < 64; off <<= 1) s += __shfl_xor(s, off, 64);
    __shared__ float red[2];
    if ((tid & 63) == 0) red[tid >> 6] = s;
    __syncthreads();
    const float mean = (red[0] + red[1]) * (1.0f / E_);

    const float dx = v.x - mean, dy = v.y - mean, dz = v.z - mean, dw = v.w - mean;
    float ss = dx * dx + dy * dy + dz * dz + dw * dw;
#pragma unroll
    for (int off = 1; off < 64; off <<= 1) ss += __shfl_xor(ss, off, 64);
    __shared__ float red2[2];
    if ((tid & 63) == 0) red2[tid >> 6] = ss;
    __syncthreads();
    const float rstd = rsqrtf((red2[0] + red2[1]) * (1.0f / E_) + 1e-5f);

    const float4 wv = *(const float4*)&w[tid * 4];
    const float4 bv = *(const float4*)&bta[tid * 4];
    u16x4 ov;
    ov[0] = f2bf(dx * rstd * wv.x + bv.x);
    ov[1] = f2bf(dy * rstd * wv.y + bv.y);
    ov[2] = f2bf(dz * rstd * wv.z + bv.z);
    ov[3] = f2bf(dw * rstd * wv.w + bv.w);
    *(u16x4*)&out[(size_t)row * E_ + tid * 4] = ov;
}

// ---------------------------------------------------------------------------
// Weight transpose + convert: W[K][N] fp32 -> WT[N][K] bf16. 32x32 LDS tiles.
// ---------------------------------------------------------------------------
__global__ __launch_bounds__(256) void wt_k(const float* __restrict__ W,
                                            unsigned short* __restrict__ WT,
                                            int K, int N)
{
    __shared__ float t[32][33];
    const int n0 = blockIdx.x * 32, k0 = blockIdx.y * 32;
    const int c = threadIdx.x & 31, r8 = threadIdx.x >> 5;
#pragma unroll
    for (int i = 0; i < 4; i++) {
        int k = r8 + i * 8;
        t[k][c] = W[(size_t)(k0 + k) * N + n0 + c];
    }
    __syncthreads();
#pragma unroll
    for (int i = 0; i < 4; i++) {
        int n = r8 + i * 8;
        WT[(size_t)(n0 + n) * K + k0 + c] = f2bf(t[c][n]);
    }
}

// ---------------------------------------------------------------------------
// bf16 MFMA GEMM: C[M,N] = A[M,K] @ BT[N,K]^T  (A,BT bf16 row-major)
// BM=WM*64, BN=WN*64, BK=32; per wave 64x64 out = 4x4 frags of 16x16x32.
// EPI: 0 = bias -> fp32 out; 1 = bias+GELU -> bf16 out;
//      2 = bias + residual, in-place fp32 resC; 3 = bias -> bf16 out;
//      5 = QKV split: cols<1024 -> qk buffer [M][1024];
//          cols>=1024 -> V transposed: vTout[b][col-1024][s] ([2][512][2048])
// ---------------------------------------------------------------------------
template<int WM, int WN, int EPI>
__global__ __launch_bounds__(WM*WN*64) void bgemm_k(
    const unsigned short* __restrict__ A,
    const unsigned short* __restrict__ BT,
    const float* __restrict__ bias,
    float* __restrict__ resC,
    unsigned short* __restrict__ outB,
    unsigned short* __restrict__ vTout,
    int M, int N, int K)
{
    constexpr int BM = WM * 64, BN = WN * 64, NW = WM * WN;
    constexpr int AISS = BM / 16, NISS = (BM + BN) / 16, IPW = NISS / NW;
    __shared__ unsigned short As[BM][32];
    __shared__ unsigned short Bs[BN][32];

    const int tid = threadIdx.x;
    const int lane = tid & 63;
    const int w = tid >> 6;
    const int wr = w / WN, wc = w % WN;
    const int brow = blockIdx.y * BM, bcol = blockIdx.x * BN;

    const int lrow = lane >> 2;          // staging: row within 16-row group
    const int lcol = (lane & 3) * 8;     // staging: bf16 col offset (16B chunks)
    const int fr = lane & 15;            // fragment row/col within 16
    const int fk = (lane >> 4) * 8;      // fragment k offset

    f32x4 acc[4][4] = {};

    for (int k0 = 0; k0 < K; k0 += 32) {
#pragma unroll
        for (int ii = 0; ii < IPW; ii++) {
            const int i = w + ii * NW;
            if (i < AISS) {
                const unsigned short* g = &A[(size_t)(brow + i * 16 + lrow) * K + k0 + lcol];
                gload_lds16(g, &As[i * 16][0]);
            } else {
                const int r = i - AISS;
                const unsigned short* g = &BT[(size_t)(bcol + r * 16 + lrow) * K + k0 + lcol];
                gload_lds16(g, &Bs[r * 16][0]);
            }
        }
        __syncthreads();

        s16x8 af[4], bfr[4];
#pragma unroll
        for (int m = 0; m < 4; m++)
            af[m] = *(const s16x8*)&As[wr * 64 + m * 16 + fr][fk];
#pragma unroll
        for (int n = 0; n < 4; n++)
            bfr[n] = *(const s16x8*)&Bs[wc * 64 + n * 16 + fr][fk];
#pragma unroll
        for (int m = 0; m < 4; m++)
#pragma unroll
            for (int n = 0; n < 4; n++)
                acc[m][n] = __builtin_amdgcn_mfma_f32_16x16x32_bf16(af[m], bfr[n], acc[m][n], 0, 0, 0);
        __syncthreads();
    }

    // C-layout: row = brow + wr*64 + m*16 + (lane>>4)*4 + j ; col = bcol + wc*64 + n*16 + (lane&15)
    const int rbase = brow + wr * 64 + (lane >> 4) * 4;
    const int cbase = bcol + wc * 64 + (lane & 15);

    if constexpr (EPI == 5) {
        if (bcol < 1024) {               // Q,K part -> [M][1024] bf16
#pragma unroll
            for (int n = 0; n < 4; n++) {
                const int col = cbase + n * 16;
                const float bz = bias[col];
#pragma unroll
                for (int m = 0; m < 4; m++)
#pragma unroll
                    for (int j = 0; j < 4; j++)
                        outB[(size_t)(rbase + m * 16 + j) * 1024 + col] =
                            f2bf(acc[m][n][j] + bz);
            }
        } else {                         // V part -> vT[b][d_full][s], packed 8B
#pragma unroll
            for (int n = 0; n < 4; n++) {
                const int col = cbase + n * 16;
                const float bz = bias[col];
                const int vcol = col - 1024;
#pragma unroll
                for (int m = 0; m < 4; m++) {
                    const int row0 = rbase + m * 16;
                    u16x4 pk;
#pragma unroll
                    for (int j = 0; j < 4; j++) pk[j] = f2bf(acc[m][n][j] + bz);
                    *(u16x4*)&vTout[(size_t)(row0 >> 11) * (512 * 2048) +
                                    (size_t)vcol * 2048 + (row0 & 2047)] = pk;
                }
            }
        }
        return;
    }

#pragma unroll
    for (int n = 0; n < 4; n++) {
        const int col = cbase + n * 16;
        const float bz = bias[col];
#pragma unroll
        for (int m = 0; m < 4; m++) {
#pragma unroll
            for (int j = 0; j < 4; j++) {
                const int row = rbase + m * 16 + j;
                float v = acc[m][n][j] + bz;
                if constexpr (EPI == 0) {
                    resC[(size_t)row * N + col] = v;
                } else if constexpr (EPI == 1) {
                    v = v * 0.5f * (1.0f + erff(v * 0.70710678118654752f));
                    outB[(size_t)row * N + col] = f2bf(v);
                } else if constexpr (EPI == 2) {
                    float* p = &resC[(size_t)row * N + col];
                    *p = *p + v;
                } else {
                    outB[(size_t)row * N + col] = f2bf(v);
                }
            }
        }
    }
}

// ---------------------------------------------------------------------------
// MFMA causal flash attention.
// qkB: [4096][1024] bf16 (Q at h*64, K at 512+h*64); vT: [b][h*64+d][s] bf16.
// Grid (32, 16): x -> q-tile (reversed for scheduling), y -> b*8+h.
// 4 waves; wave w owns q-rows q0+w*16..+15. Per k-tile (64 keys):
//   QK^T: 8 MFMA -> S strip 16x64 (fp32, C-layout)
//   online softmax per row (16-lane shfl groups), P -> bf16 -> swizzled LDS
//   PV: 8 MFMA with A=P (LDS), B=V^T rows (LDS)
// K/V^T tiles reg-staged to LDS with XOR swizzle ((row&7) chunk xor)
// -> conflict-free ds_read_b128 fragments (T2).
// ---------------------------------------------------------------------------
__global__ __launch_bounds__(256) void fattn_k(const unsigned short* __restrict__ qkB,
                                               const unsigned short* __restrict__ vT,
                                               unsigned short* __restrict__ o)
{
    __shared__ unsigned short Kl[64 * 64];   // [k][d] swizzled
    __shared__ unsigned short Vl[64 * 64];   // [d][k] swizzled (from vT)
    __shared__ unsigned short Pl[4 * 16 * 64]; // per-wave P, swizzled

    const int tid = threadIdx.x;
    const int lane = tid & 63;
    const int w = tid >> 6;
    const int qi = (S_ / 64 - 1) - blockIdx.x;  // long blocks dispatch first
    const int q0 = qi * 64;
    const int bh = blockIdx.y;
    const int b = bh >> 3, hh = bh & 7;
    const int l15 = lane & 15, l4 = lane >> 4;

    // Q fragments (A-layout): row q0+w*16+l15, k-chunk l4*8 (+ks*32)
    s16x8 qf[2];
    {
        const unsigned short* qp =
            &qkB[(size_t)(b * S_ + q0 + w * 16 + l15) * 1024 + hh * 64 + l4 * 8];
        qf[0] = *(const s16x8*)&qp[0];
        qf[1] = *(const s16x8*)&qp[32];
    }

    f32x4 oacc[4] = {};
    float mx[4]   = {-3.4e38f, -3.4e38f, -3.4e38f, -3.4e38f};
    float lsum[4] = {0.f, 0.f, 0.f, 0.f};

    for (int kt = 0; kt <= qi; kt++) {
        const int k0 = kt * 64;
        // stage K[k][d] and V^T[d][k] tiles (2 x 16B chunks each per thread)
#pragma unroll
        for (int p = 0; p < 2; p++) {
            const int c = p * 256 + tid;     // chunk 0..511
            const int rr = c >> 3, kc = c & 7;
            uint4 kg = *(const uint4*)&qkB[(size_t)(b * S_ + k0 + rr) * 1024 + 512 + hh * 64 + kc * 8];
            *(uint4*)&Kl[rr * 64 + ((kc ^ (rr & 7)) * 8)] = kg;
            uint4 vg = *(const uint4*)&vT[(size_t)(bh * 64 + rr) * S_ + k0 + kc * 8];
            *(uint4*)&Vl[rr * 64 + ((kc ^ (rr & 7)) * 8)] = vg;
        }
        __syncthreads();

        // QK^T strip: S[16 q][64 k]
        f32x4 sacc[4] = {};
#pragma unroll
        for (int ks = 0; ks < 2; ks++) {
#pragma unroll
            for (int n = 0; n < 4; n++) {
                const int rk = n * 16 + l15;
                s16x8 kf = *(const s16x8*)&Kl[rk * 64 + (((ks * 4 + l4) ^ (rk & 7)) * 8)];
                sacc[n] = __builtin_amdgcn_mfma_f32_16x16x32_bf16(qf[ks], kf, sacc[n], 0, 0, 0);
            }
        }

        // online softmax (row = q0+w*16+l4*4+j, 16 cols per lane-group)
        const bool diag = (kt == qi);
        float pv[4][4];
#pragma unroll
        for (int j = 0; j < 4; j++) {
            const int lrow = w * 16 + l4 * 4 + j;   // row within q-tile
            float rm = -3.4e38f;
#pragma unroll
            for (int n = 0; n < 4; n++) {
                float s = sacc[n][j] * 0.125f;
                if (diag && (n * 16 + l15 > lrow)) s = -3.4e38f;
                pv[n][j] = s;
                rm = fmaxf(rm, s);
            }
            rm = fmaxf(rm, __shfl_xor(rm, 1, 64));
            rm = fmaxf(rm, __shfl_xor(rm, 2, 64));
            rm = fmaxf(rm, __shfl_xor(rm, 4, 64));
            rm = fmaxf(rm, __shfl_xor(rm, 8, 64));
            const float mn = fmaxf(mx[j], rm);
            const float sc = __expf(mx[j] - mn);
            mx[j] = mn;
            float ps = 0.f;
#pragma unroll
            for (int n = 0; n < 4; n++) {
                const float e = __expf(pv[n][j] - mn);
                pv[n][j] = e;
                ps += e;
            }
            ps += __shfl_xor(ps, 1, 64);
            ps += __shfl_xor(ps, 2, 64);
            ps += __shfl_xor(ps, 4, 64);
            ps += __shfl_xor(ps, 8, 64);
            lsum[j] = lsum[j] * sc + ps;
#pragma unroll
            for (int n = 0; n < 4; n++) oacc[n][j] *= sc;
            // P (C-layout) -> swizzled per-wave LDS (A-layout readable)
            const int r = l4 * 4 + j;
#pragma unroll
            for (int n = 0; n < 4; n++) {
                const int cc = n * 16 + l15;
                Pl[w * 1024 + r * 64 + (cc ^ ((r & 7) << 3))] = f2bf(pv[n][j]);
            }
        }

        // PV: O += P @ V   (A = P from LDS, B = V^T rows from LDS)
#pragma unroll
        for (int ks = 0; ks < 2; ks++) {
            s16x8 pf = *(const s16x8*)&Pl[w * 1024 + l15 * 64 + (((ks * 4 + l4) ^ (l15 & 7)) * 8)];
#pragma unroll
            for (int n = 0; n < 4; n++) {
                const int rv = n * 16 + l15;
                s16x8 vf = *(const s16x8*)&Vl[rv * 64 + (((ks * 4 + l4) ^ (rv & 7)) * 8)];
                oacc[n] = __builtin_amdgcn_mfma_f32_16x16x32_bf16(pf, vf, oacc[n], 0, 0, 0);
            }
        }
        __syncthreads();
    }

    // epilogue: O /= l, bf16 store
#pragma unroll
    for (int j = 0; j < 4; j++) {
        const float inv = 1.0f / lsum[j];
        const int grow = q0 + w * 16 + l4 * 4 + j;
        unsigned short* op = &o[(size_t)(b * S_ + grow) * E_ + hh * 64 + l15];
#pragma unroll
        for (int n = 0; n < 4; n++)
            op[n * 16] = f2bf(oacc[n][j] * inv);
    }
}

// ---------------------------------------------------------------------------
// Host-side launch
// ---------------------------------------------------------------------------
extern "C" void kernel_launch(void* const* d_in, const int* in_sizes, int n_in,
                              void* d_out, int out_size, void* d_ws, size_t ws_size,
                              hipStream_t stream)
{
    (void)in_sizes; (void)n_in; (void)out_size; (void)ws_size;

    const int*   x     = (const int*)d_in[0];
    const float* tok   = (const float*)d_in[1];
    const float* pos   = (const float*)d_in[2];
    const float* ln1w  = (const float*)d_in[3];
    const float* ln1b  = (const float*)d_in[4];
    const float* qkvw  = (const float*)d_in[5];
    const float* qkvb  = (const float*)d_in[6];
    const float* projw = (const float*)d_in[7];
    const float* projb = (const float*)d_in[8];
    const float* ln2w  = (const float*)d_in[9];
    const float* ln2b  = (const float*)d_in[10];
    const float* ff1w  = (const float*)d_in[11];
    const float* ff1b  = (const float*)d_in[12];
    const float* ff2w  = (const float*)d_in[13];
    const float* ff2b  = (const float*)d_in[14];
    const float* lnfw  = (const float*)d_in[15];
    const float* lnfb  = (const float*)d_in[16];
    const float* outw  = (const float*)d_in[17];
    const float* outb  = (const float*)d_in[18];

    float* out = (float*)d_out;
    char*  w8  = (char*)d_ws;

    // workspace layout (78.9 MB total; round-1/4 proved >= 83.9 MB available)
    float*          h   = (float*)w8;                          //  8 MB fp32 residual
    unsigned short* qkB = (unsigned short*)(w8 + 8388608);     //  8 MB [4096][1024] Q,K
    unsigned short* vT  = (unsigned short*)(w8 + 16777216);    //  4 MB [2][512][2048] V^T
    unsigned short* yb  = (unsigned short*)(w8 + 20971520);    //  4 MB LN out
    unsigned short* ffb = (unsigned short*)(w8 + 25165824);    // 16 MB FF1 out
    unsigned short* ob  = (unsigned short*)(w8 + 41943040);    //  4 MB attn out
    unsigned short* wt  = (unsigned short*)(w8 + 46137344);    // 32.77 MB weight^T

    embed_k<<<M_, 128, 0, stream>>>(x, tok, pos, h);

    for (int l = 0; l < L_; l++) {
        ln_k<<<M_, 128, 0, stream>>>(h, ln1w + (size_t)l * E_, ln1b + (size_t)l * E_, yb);

        wt_k<<<dim3(3 * E_ / 32, E_ / 32), 256, 0, stream>>>(
            qkvw + (size_t)l * E_ * 3 * E_, wt, E_, 3 * E_);
        bgemm_k<2, 2, 5><<<dim3(3 * E_ / 128, M_ / 128), 256, 0, stream>>>(
            yb, wt, qkvb + (size_t)l * 3 * E_, nullptr, qkB, vT, M_, 3 * E_, E_);

        fattn_k<<<dim3(S_ / 64, B_ * H_), 256, 0, stream>>>(qkB, vT, ob);

        wt_k<<<dim3(E_ / 32, E_ / 32), 256, 0, stream>>>(
            projw + (size_t)l * E_ * E_, wt, E_, E_);
        bgemm_k<2, 1, 2><<<dim3(E_ / 64, M_ / 128), 128, 0, stream>>>(
            ob, wt, projb + (size_t)l * E_, h, nullptr, nullptr, M_, E_, E_);

        ln_k<<<M_, 128, 0, stream>>>(h, ln2w + (size_t)l * E_, ln2b + (size_t)l * E_, yb);

        wt_k<<<dim3(F_ / 32, E_ / 32), 256, 0, stream>>>(
            ff1w + (size_t)l * E_ * F_, wt, E_, F_);
        bgemm_k<2, 2, 1><<<dim3(F_ / 128, M_ / 128), 256, 0, stream>>>(
            yb, wt, ff1b + (size_t)l * F_, nullptr, ffb, nullptr, M_, F_, E_);

        wt_k<<<dim3(E_ / 32, F_ / 32), 256, 0, stream>>>(
            ff2w + (size_t)l * F_ * E_, wt, F_, E_);
        bgemm_k<2, 1, 2><<<dim3(E_ / 64, M_ / 128), 128, 0, stream>>>(
            ffb, wt, ff2b + (size_t)l * E_, h, nullptr, nullptr, M_, E_, F_);
    }

    ln_k<<<M_, 128, 0, stream>>>(h, lnfw, lnfb, yb);

    wt_k<<<dim3(V_ / 32, E_ / 32), 256, 0, stream>>>(outw, wt, E_, V_);
    bgemm_k<2, 2, 0><<<dim3(V_ / 128, M_ / 128), 256, 0, stream>>>(
        yb, wt, outb, out, nullptr, nullptr, M_, V_, E_);
}